// Round 9
// baseline (223.796 us; speedup 1.0000x reference)
//
#include <hip/hip_runtime.h>

// p/v trajectory double-scan, K = 2^23 fp32 3-vectors. Reduce-then-scan, 2 kernels + memset.
// Aligned-stream formulation: z_m = f[m]; E_i = excl prefix(z); H_i = sum_{m<=i} E_m.
// S_i = f0 + E_i, T_i = (i+1) f0 + H_i;
//   v_i = v0 + Cc*S_i + GZ*(i+1) e3
//   p_i = p0 + DT*(i+1)*v0 + DT*Cc*T_i - DT/2*Cc*S_i + DT/2*GZ*(i+1)^2 e3
// Segment operator on (A = sum z, W = sum of seg-local excl prefixes):
//   concat X(left) Y(right): W = W_X + L_Y*A_X + W_Y ; A = A_X + A_Y.
// Lessons: r3 — nt strided stores amplify HBM writes 2.6x; r8 — even CACHED strided
//   stores cost +14us (L2 request fan-out): outputs MUST leave lane-consecutive via
//   LDS staging + nt. r5 — agent-scope SPIN loops serialize across XCDs (one-shot
//   last-block atomic is fine). r6 — strided input loads and tiny k_agg blocks regress.

namespace {
constexpr int  KE    = 8388608;               // 2^23
constexpr int  CHUNK = 2048;                  // elements per scan block
constexpr int  NB    = KE / CHUNK;            // 4096
constexpr int  BLOCK = 256;
constexpr int  R     = CHUNK / BLOCK;         // 8 elements/thread
constexpr int  NF4   = 3 * CHUNK / 4;         // 1536 f4 per chunk per output
constexpr int  BPT2  = NB / BLOCK;            // 16 chunks per thread in last-block prefix
constexpr float DTc = 0.01f;
constexpr float Cc  = 0.01f / 1.5f;           // DT/M
constexpr float GZ  = -0.01f * 9.81f;         // DT * (-G)
typedef float f32x4 __attribute__((ext_vector_type(4)));
__device__ __forceinline__ int physf4(int q) { return 7 * (q / 6) + q % 6; }
}

// ---------- k_aggpre: per-chunk aggregates + last-block computes all chunk prefixes ----------
__global__ __launch_bounds__(BLOCK) void k_aggpre(const float* __restrict__ f,
                                                  float* __restrict__ W,
                                                  float* __restrict__ W2,
                                                  unsigned int* __restrict__ cnt) {
  const int b = blockIdx.x, t = threadIdx.x;
  const int lane = t & 63, wid = t >> 6;

  // --- aggregate phase (r4-proven geometry) ---
  const f32x4* src = (const f32x4*)(f + (size_t)3 * CHUNK * b);
  float A[3] = {0.f, 0.f, 0.f}, Bw[3] = {0.f, 0.f, 0.f};
#pragma unroll
  for (int it = 0; it < 2; ++it) {
    int q3 = it * BLOCK + t;                  // triple index, elems 4q3..4q3+3
    f32x4 d0 = src[3 * q3], d1 = src[3 * q3 + 1], d2 = src[3 * q3 + 2];
    float j0 = (float)(4 * q3), j1 = j0 + 1.f, j2 = j0 + 2.f, j3 = j0 + 3.f;
    A[0] += d0.x; Bw[0] += j0 * d0.x;  A[1] += d0.y; Bw[1] += j0 * d0.y;  A[2] += d0.z; Bw[2] += j0 * d0.z;
    A[0] += d0.w; Bw[0] += j1 * d0.w;  A[1] += d1.x; Bw[1] += j1 * d1.x;  A[2] += d1.y; Bw[2] += j1 * d1.y;
    A[0] += d1.z; Bw[0] += j2 * d1.z;  A[1] += d1.w; Bw[1] += j2 * d1.w;  A[2] += d2.x; Bw[2] += j2 * d2.x;
    A[0] += d2.y; Bw[0] += j3 * d2.y;  A[1] += d2.z; Bw[1] += j3 * d2.z;  A[2] += d2.w; Bw[2] += j3 * d2.w;
  }
#pragma unroll
  for (int d = 32; d >= 1; d >>= 1) {
#pragma unroll
    for (int q = 0; q < 3; ++q) {
      A[q]  += __shfl_down(A[q], d);
      Bw[q] += __shfl_down(Bw[q], d);
    }
  }
  __shared__ float wag[4][6];
  __shared__ int isLast;
  if (lane == 0) {
#pragma unroll
    for (int q = 0; q < 3; ++q) { wag[wid][q] = A[q]; wag[wid][3 + q] = Bw[q]; }
  }
  __syncthreads();
  if (t == 0) {
    // publish aggregates with agent-scope stores (readable from any XCD)
#pragma unroll
    for (int q = 0; q < 3; ++q) {
      float a  = wag[0][q] + wag[1][q] + wag[2][q] + wag[3][q];
      float bw = wag[0][3 + q] + wag[1][3 + q] + wag[2][3 + q] + wag[3][3 + q];
      __hip_atomic_store(&W[q * NB + b], a, __ATOMIC_RELAXED, __HIP_MEMORY_SCOPE_AGENT);
      __hip_atomic_store(&W[(3 + q) * NB + b], bw, __ATOMIC_RELAXED, __HIP_MEMORY_SCOPE_AGENT);
    }
    unsigned int old = __hip_atomic_fetch_add(cnt, 1u, __ATOMIC_ACQ_REL, __HIP_MEMORY_SCOPE_AGENT);
    isLast = (old == (unsigned int)(NB - 1));
  }
  __syncthreads();
  if (!isLast) return;

  // --- last block: cross-chunk exclusive (Eg, Hg) prefixes, fp64, 256 threads ---
  __threadfence();   // acquire-side: invalidate caches before reading remote W
  double tA[3] = {0, 0, 0}, tW[3] = {0, 0, 0};
#pragma unroll
  for (int k = 0; k < BPT2; ++k) {
    const int c = BPT2 * t + k;
#pragma unroll
    for (int q = 0; q < 3; ++q) {
      const double a  = (double)__hip_atomic_load(&W[q * NB + c], __ATOMIC_RELAXED, __HIP_MEMORY_SCOPE_AGENT);
      const double bw = (double)__hip_atomic_load(&W[(3 + q) * NB + c], __ATOMIC_RELAXED, __HIP_MEMORY_SCOPE_AGENT);
      const double wc = (double)(CHUNK - 1) * a - bw;      // chunk-local W
      tW[q] += (double)((BPT2 - 1 - k) * CHUNK) * a + wc;
      tA[q] += a;
    }
  }
#pragma unroll
  for (int d = 1; d < 64; d <<= 1) {
    double pA[3], pW[3];
#pragma unroll
    for (int q = 0; q < 3; ++q) { pA[q] = __shfl_up(tA[q], d); pW[q] = __shfl_up(tW[q], d); }
    if (lane >= d) {
      const double Ld = (double)(d * BPT2 * CHUNK);
#pragma unroll
      for (int q = 0; q < 3; ++q) { tW[q] = pW[q] + Ld * pA[q] + tW[q]; tA[q] += pA[q]; }
    }
  }
  double eA[3], eW[3];
#pragma unroll
  for (int q = 0; q < 3; ++q) { eA[q] = __shfl_up(tA[q], 1); eW[q] = __shfl_up(tW[q], 1); }
  if (lane == 0) {
#pragma unroll
    for (int q = 0; q < 3; ++q) { eA[q] = 0.0; eW[q] = 0.0; }
  }
  __shared__ double wagd[4][6];
  if (lane == 63) {
#pragma unroll
    for (int q = 0; q < 3; ++q) { wagd[wid][q] = tA[q]; wagd[wid][3 + q] = tW[q]; }
  }
  __syncthreads();
  double oA[3] = {0, 0, 0}, oW[3] = {0, 0, 0};
  for (int w = 0; w < wid; ++w) {
#pragma unroll
    for (int q = 0; q < 3; ++q) oW[q] = oW[q] + (double)(64 * BPT2 * CHUNK) * oA[q] + wagd[w][3 + q];
#pragma unroll
    for (int q = 0; q < 3; ++q) oA[q] += wagd[w][q];
  }
  double Ex[3], Hx[3];
#pragma unroll
  for (int q = 0; q < 3; ++q) {
    Ex[q] = oA[q] + eA[q];
    Hx[q] = oW[q] + (double)(lane * BPT2 * CHUNK) * oA[q] + eW[q];
  }
#pragma unroll
  for (int k = 0; k < BPT2; ++k) {
    const int c = BPT2 * t + k;
#pragma unroll
    for (int q = 0; q < 3; ++q) {
      W2[6 * c + q]     = (float)Ex[q];          // Eg: excl elem-sum before chunk c
      W2[6 * c + 3 + q] = (float)Hx[q];          // Hg: sum of E over elems before chunk c
      const double a  = (double)__hip_atomic_load(&W[q * NB + c], __ATOMIC_RELAXED, __HIP_MEMORY_SCOPE_AGENT);
      const double bw = (double)__hip_atomic_load(&W[(3 + q) * NB + c], __ATOMIC_RELAXED, __HIP_MEMORY_SCOPE_AGENT);
      const double wc = (double)(CHUNK - 1) * a - bw;
      Hx[q] += (double)CHUNK * Ex[q] + wc;
      Ex[q] += a;
    }
  }
  // kernel end flushes L2 -> W2 visible to k_scan
}

// ---------- k_scan: r4-proven body (LDS transpose IO, nt lane-consecutive stores) ----------
__global__ __launch_bounds__(BLOCK, 5) void k_scan(const float* __restrict__ f,
                                                   const float* __restrict__ W2,
                                                   const float* __restrict__ p0v,
                                                   const float* __restrict__ v0v,
                                                   float* __restrict__ out) {
  const int b = blockIdx.x, t = threadIdx.x;
  const int lane = t & 63, wid = t >> 6;
  const long start = (long)b * CHUNK;

  // hoisted uniform loads (latency hides under staging)
  float Wg[6];
#pragma unroll
  for (int u = 0; u < 6; ++u) Wg[u] = W2[6 * b + u];
  const float f0[3] = {f[0], f[1], f[2]};
  const float p0x = p0v[0], p0y = p0v[1], p0z = p0v[2];
  const float v0x = v0v[0], v0y = v0v[1], v0z = v0v[2];

  __shared__ f32x4 buf[7 * BLOCK];    // 28672 B padded transpose buffer
  __shared__ float wag[4][6];

  // ---- 1. coalesced global load -> LDS (blocked-padded layout)
  {
    const f32x4* src = (const f32x4*)(f + 3 * start);
#pragma unroll
    for (int it = 0; it < 6; ++it) {
      const int q = t + BLOCK * it;
      buf[physf4(q)] = src[q];
    }
  }
  __syncthreads();

  // ---- 2. thread's 8 elements = 6 float4 LDS reads at stride-7 base
  float z[3 * R];
#pragma unroll
  for (int u = 0; u < 6; ++u) {
    f32x4 d = buf[7 * t + u];
    z[4 * u] = d.x; z[4 * u + 1] = d.y; z[4 * u + 2] = d.z; z[4 * u + 3] = d.w;
  }

  // per-thread aggregates: A = sum z, W = sum (R-1-e)*z
  float tS[3] = {0, 0, 0}, tT[3] = {0, 0, 0};
#pragma unroll
  for (int e = 0; e < R; ++e) {
    const float wt = (float)(R - 1 - e);
#pragma unroll
    for (int q = 0; q < 3; ++q) { float v = z[3 * e + q]; tS[q] += v; tT[q] += wt * v; }
  }
  // wave Kogge-Stone with (A,W) operator
#pragma unroll
  for (int d = 1; d < 64; d <<= 1) {
    float pS[3], pT[3];
#pragma unroll
    for (int q = 0; q < 3; ++q) { pS[q] = __shfl_up(tS[q], d); pT[q] = __shfl_up(tT[q], d); }
    if (lane >= d) {
      const float Ld = (float)(R * d);
#pragma unroll
      for (int q = 0; q < 3; ++q) { tT[q] = pT[q] + Ld * pS[q] + tT[q]; tS[q] += pS[q]; }
    }
  }
  float eS[3], eT[3];
#pragma unroll
  for (int q = 0; q < 3; ++q) { eS[q] = __shfl_up(tS[q], 1); eT[q] = __shfl_up(tT[q], 1); }
  if (lane == 0) {
#pragma unroll
    for (int q = 0; q < 3; ++q) { eS[q] = 0.f; eT[q] = 0.f; }
  }
  if (lane == 63) {
#pragma unroll
    for (int q = 0; q < 3; ++q) { wag[wid][q] = tS[q]; wag[wid][3 + q] = tT[q]; }
  }
  __syncthreads();
  float oS[3] = {0, 0, 0}, oT[3] = {0, 0, 0};
  for (int w = 0; w < wid; ++w) {        // wave segment = 64*R = 512
#pragma unroll
    for (int q = 0; q < 3; ++q) oT[q] = oT[q] + 512.0f * oS[q] + wag[w][3 + q];
#pragma unroll
    for (int q = 0; q < 3; ++q) oS[q] += wag[w][q];
  }
  // absolute thread-entry (E0, H0)
  float E0[3], H0[3];
#pragma unroll
  for (int q = 0; q < 3; ++q) {
    E0[q] = Wg[q] + oS[q] + eS[q];
    H0[q] = Wg[3 + q] + (float)(R * t) * Wg[q] + (oT[q] + (float)(R * lane) * oS[q] + eT[q]);
  }

  // ---- 3. fused epilogue: p -> LDS (thread-local WAR on own slots), v -> registers
  const float a1 = DTc * Cc, a2 = 0.5f * DTc * Cc, c3 = 0.5f * DTc * GZ;
  float lsum[3] = {0, 0, 0};
  float runH[3] = {H0[0], H0[1], H0[2]};
  float ve[3 * R];
#pragma unroll
  for (int g = 0; g < 2; ++g) {
    float pe[12];
#pragma unroll
    for (int e4 = 0; e4 < 4; ++e4) {
      const int e = 4 * g + e4;
      const float n1 = (float)(int)(start + t * R + e + 1);   // <= 2^23, exact
      float S_[3], T_[3];
#pragma unroll
      for (int q = 0; q < 3; ++q) {
        const float curE = E0[q] + lsum[q];    // E_i
        runH[q] += curE;                       // H_i
        S_[q] = f0[q] + curE;
        T_[q] = n1 * f0[q] + runH[q];
        lsum[q] += z[3 * e + q];
      }
      ve[3 * e + 0] = v0x + Cc * S_[0];
      ve[3 * e + 1] = v0y + Cc * S_[1];
      ve[3 * e + 2] = v0z + Cc * S_[2] + GZ * n1;
      pe[3 * e4 + 0] = p0x + DTc * n1 * v0x + a1 * T_[0] - a2 * S_[0];
      pe[3 * e4 + 1] = p0y + DTc * n1 * v0y + a1 * T_[1] - a2 * S_[1];
      pe[3 * e4 + 2] = p0z + DTc * n1 * v0z + a1 * T_[2] - a2 * S_[2] + c3 * n1 * n1;
    }
#pragma unroll
    for (int u = 0; u < 3; ++u) {
      f32x4 pv = {pe[4 * u], pe[4 * u + 1], pe[4 * u + 2], pe[4 * u + 3]};
      buf[7 * t + 3 * g + u] = pv;
    }
  }
  __syncthreads();

  // ---- 4. coalesced nontemporal store of p
  {
    f32x4* dst = (f32x4*)out + (size_t)NF4 * b;
#pragma unroll
    for (int it = 0; it < 6; ++it) {
      const int q = t + BLOCK * it;
      f32x4 d = buf[physf4(q)];
      __builtin_nontemporal_store(d, dst + q);
    }
  }
  __syncthreads();

  // ---- 5. v through the same buffer
#pragma unroll
  for (int u = 0; u < 6; ++u) {
    f32x4 vv = {ve[4 * u], ve[4 * u + 1], ve[4 * u + 2], ve[4 * u + 3]};
    buf[7 * t + u] = vv;
  }
  __syncthreads();
  {
    f32x4* dst = (f32x4*)(out + (size_t)3 * KE) + (size_t)NF4 * b;
#pragma unroll
    for (int it = 0; it < 6; ++it) {
      const int q = t + BLOCK * it;
      f32x4 d = buf[physf4(q)];
      __builtin_nontemporal_store(d, dst + q);
    }
  }
}

extern "C" void kernel_launch(void* const* d_in, const int* in_sizes, int n_in,
                              void* d_out, int out_size, void* d_ws, size_t ws_size,
                              hipStream_t stream) {
  const float* f  = (const float*)d_in[0];
  const float* p0 = (const float*)d_in[1];
  const float* v0 = (const float*)d_in[2];
  float* out = (float*)d_out;
  unsigned int* cnt = (unsigned int*)d_ws;       // 1 uint (64B-aligned slot)
  float* W   = (float*)d_ws + 16;                // 6*NB floats: A[3][NB], Bw[3][NB]
  float* W2  = W + 6 * NB;                       // 6*NB floats: per-chunk (Eg[3], Hg[3])
  hipMemsetAsync(cnt, 0, sizeof(unsigned int), stream);
  k_aggpre<<<NB, BLOCK, 0, stream>>>(f, W, W2, cnt);
  k_scan  <<<NB, BLOCK, 0, stream>>>(f, W2, p0, v0, out);
}

// Round 10
// 75.375 us; speedup vs baseline: 2.9691x; 2.9691x over previous
//
#include <hip/hip_runtime.h>

// p/v trajectory double-scan, K = 2^23 fp32 3-vectors. Reduce-then-scan, 3 kernels.
// Aligned-stream formulation: z_m = f[m]; E_i = excl prefix(z); H_i = sum_{m<=i} E_m.
// S_i = f0 + E_i, T_i = (i+1) f0 + H_i;
//   v_i = v0 + Cc*S_i + GZ*(i+1) e3
//   p_i = p0 + DT*(i+1)*v0 + DT*Cc*T_i - DT/2*Cc*S_i + DT/2*GZ*(i+1)^2 e3
// Segment operator on (A = sum z, W = sum of seg-local excl prefixes):
//   concat X(left) Y(right): W = W_X + L_Y*A_X + W_Y ; A = A_X + A_Y.
// Lessons: r3 — nt strided stores amplify HBM writes 2.6x; r8 — cached strided
//   stores cost +14us (L2 request fan-out): outputs leave lane-consecutive via LDS+nt.
//   r5/r9 — ANY per-block agent-scope acquire/release (spin or one-shot acq_rel
//   atomic) serializes across the 8 XCDs: keep 3 plain kernels (graph-replay gaps ~0).
//   r6 — strided input loads and tiny k_agg blocks regress.
// This round: output staging made WAVE-LOCAL (each wave's own 448-f4 region +
//   s_waitcnt lgkmcnt(0)) -> block barriers 5 -> 2.

namespace {
constexpr int  KE    = 8388608;               // 2^23
constexpr int  CHUNK = 2048;                  // elements per scan block
constexpr int  NB    = KE / CHUNK;            // 4096
constexpr int  BLOCK = 256;
constexpr int  R     = CHUNK / BLOCK;         // 8 elements/thread
constexpr int  NF4   = 3 * CHUNK / 4;         // 1536 f4 per chunk per output
constexpr int  PRET  = 1024;                  // k_pre threads
constexpr int  BPT   = NB / PRET;             // 4 chunks per k_pre thread
constexpr float DTc = 0.01f;
constexpr float Cc  = 0.01f / 1.5f;           // DT/M
constexpr float GZ  = -0.01f * 9.81f;         // DT * (-G)
typedef float f32x4 __attribute__((ext_vector_type(4)));
__device__ __forceinline__ int physf4(int q) { return 7 * (q / 6) + q % 6; }
}

// ---------- k_agg: per-chunk A = sum z, Bw = sum j*z  (r4-proven geometry) ----------
__global__ __launch_bounds__(BLOCK) void k_agg(const float* __restrict__ f,
                                               float* __restrict__ W) {
  const int b = blockIdx.x, t = threadIdx.x;
  const int lane = t & 63, wid = t >> 6;
  const f32x4* src = (const f32x4*)(f + (size_t)3 * CHUNK * b);
  float A[3] = {0.f, 0.f, 0.f}, Bw[3] = {0.f, 0.f, 0.f};
#pragma unroll
  for (int it = 0; it < 2; ++it) {
    int q3 = it * BLOCK + t;                  // triple index, elems 4q3..4q3+3
    f32x4 d0 = src[3 * q3], d1 = src[3 * q3 + 1], d2 = src[3 * q3 + 2];
    float j0 = (float)(4 * q3), j1 = j0 + 1.f, j2 = j0 + 2.f, j3 = j0 + 3.f;
    A[0] += d0.x; Bw[0] += j0 * d0.x;  A[1] += d0.y; Bw[1] += j0 * d0.y;  A[2] += d0.z; Bw[2] += j0 * d0.z;
    A[0] += d0.w; Bw[0] += j1 * d0.w;  A[1] += d1.x; Bw[1] += j1 * d1.x;  A[2] += d1.y; Bw[2] += j1 * d1.y;
    A[0] += d1.z; Bw[0] += j2 * d1.z;  A[1] += d1.w; Bw[1] += j2 * d1.w;  A[2] += d2.x; Bw[2] += j2 * d2.x;
    A[0] += d2.y; Bw[0] += j3 * d2.y;  A[1] += d2.z; Bw[1] += j3 * d2.z;  A[2] += d2.w; Bw[2] += j3 * d2.w;
  }
#pragma unroll
  for (int d = 32; d >= 1; d >>= 1) {
#pragma unroll
    for (int q = 0; q < 3; ++q) {
      A[q]  += __shfl_down(A[q], d);
      Bw[q] += __shfl_down(Bw[q], d);
    }
  }
  __shared__ float wag[4][6];
  if (lane == 0) {
#pragma unroll
    for (int q = 0; q < 3; ++q) { wag[wid][q] = A[q]; wag[wid][3 + q] = Bw[q]; }
  }
  __syncthreads();
  if (t == 0) {
#pragma unroll
    for (int q = 0; q < 3; ++q) {
      W[q * NB + b]       = wag[0][q] + wag[1][q] + wag[2][q] + wag[3][q];
      W[(3 + q) * NB + b] = wag[0][3 + q] + wag[1][3 + q] + wag[2][3 + q] + wag[3][3 + q];
    }
  }
}

// ---------- k_pre: cross-chunk exclusive (Eg, Hg) per chunk, fp64 (r4-proven) ----------
__global__ __launch_bounds__(PRET) void k_pre(const float* __restrict__ W,
                                              float* __restrict__ W2) {
  const int t = threadIdx.x, lane = t & 63, wid = t >> 6;   // 16 waves
  double Ac[BPT][3], Wc[BPT][3];
#pragma unroll
  for (int k = 0; k < BPT; ++k) {
    const int c = BPT * t + k;
#pragma unroll
    for (int q = 0; q < 3; ++q) {
      double a  = (double)W[q * NB + c];
      double bw = (double)W[(3 + q) * NB + c];
      Ac[k][q] = a;
      Wc[k][q] = (double)(CHUNK - 1) * a - bw;   // sum (CHUNK-1-j)*z over chunk
    }
  }
  double tA[3] = {0, 0, 0}, tW[3] = {0, 0, 0};
#pragma unroll
  for (int k = 0; k < BPT; ++k) {
#pragma unroll
    for (int q = 0; q < 3; ++q) {
      tW[q] += (double)((BPT - 1 - k) * CHUNK) * Ac[k][q] + Wc[k][q];
      tA[q] += Ac[k][q];
    }
  }
#pragma unroll
  for (int d = 1; d < 64; d <<= 1) {
    double pA[3], pW[3];
#pragma unroll
    for (int q = 0; q < 3; ++q) { pA[q] = __shfl_up(tA[q], d); pW[q] = __shfl_up(tW[q], d); }
    if (lane >= d) {
      const double Ld = (double)(d * BPT * CHUNK);
#pragma unroll
      for (int q = 0; q < 3; ++q) { tW[q] = pW[q] + Ld * pA[q] + tW[q]; tA[q] += pA[q]; }
    }
  }
  double eA[3], eW[3];
#pragma unroll
  for (int q = 0; q < 3; ++q) { eA[q] = __shfl_up(tA[q], 1); eW[q] = __shfl_up(tW[q], 1); }
  if (lane == 0) {
#pragma unroll
    for (int q = 0; q < 3; ++q) { eA[q] = 0.0; eW[q] = 0.0; }
  }
  __shared__ double wagd[16][6];
  if (lane == 63) {
#pragma unroll
    for (int q = 0; q < 3; ++q) { wagd[wid][q] = tA[q]; wagd[wid][3 + q] = tW[q]; }
  }
  __syncthreads();
  double oA[3] = {0, 0, 0}, oW[3] = {0, 0, 0};
  for (int w = 0; w < wid; ++w) {
#pragma unroll
    for (int q = 0; q < 3; ++q) oW[q] = oW[q] + (double)(64 * BPT * CHUNK) * oA[q] + wagd[w][3 + q];
#pragma unroll
    for (int q = 0; q < 3; ++q) oA[q] += wagd[w][q];
  }
  double Ex[3], Hx[3];
#pragma unroll
  for (int q = 0; q < 3; ++q) {
    Ex[q] = oA[q] + eA[q];
    Hx[q] = oW[q] + (double)(lane * BPT * CHUNK) * oA[q] + eW[q];
  }
#pragma unroll
  for (int k = 0; k < BPT; ++k) {
    const int c = BPT * t + k;
#pragma unroll
    for (int q = 0; q < 3; ++q) {
      W2[6 * c + q]     = (float)Ex[q];          // Eg: excl elem-sum before chunk c
      W2[6 * c + 3 + q] = (float)Hx[q];          // Hg: sum of E over elems before chunk c
      Hx[q] += (double)CHUNK * Ex[q] + Wc[k][q];
      Ex[q] += Ac[k][q];
    }
  }
}

// ---------- k_scan: r4 body, output staging wave-local (2 block barriers) ----------
__global__ __launch_bounds__(BLOCK, 5) void k_scan(const float* __restrict__ f,
                                                   const float* __restrict__ W2,
                                                   const float* __restrict__ p0v,
                                                   const float* __restrict__ v0v,
                                                   float* __restrict__ out) {
  const int b = blockIdx.x, t = threadIdx.x;
  const int lane = t & 63, wid = t >> 6;
  const long start = (long)b * CHUNK;

  // hoisted uniform loads (latency hides under staging)
  float Wg[6];
#pragma unroll
  for (int u = 0; u < 6; ++u) Wg[u] = W2[6 * b + u];
  const float f0[3] = {f[0], f[1], f[2]};
  const float p0x = p0v[0], p0y = p0v[1], p0z = p0v[2];
  const float v0x = v0v[0], v0y = v0v[1], v0z = v0v[2];

  __shared__ f32x4 buf[7 * BLOCK];    // 28672 B padded transpose buffer
  __shared__ float wag[4][6];

  // ---- 1. coalesced global load -> LDS (blocked-padded layout)
  {
    const f32x4* src = (const f32x4*)(f + 3 * start);
#pragma unroll
    for (int it = 0; it < 6; ++it) {
      const int q = t + BLOCK * it;
      buf[physf4(q)] = src[q];
    }
  }
  __syncthreads();                               // barrier 1

  // ---- 2. thread's 8 elements = 6 float4 LDS reads at stride-7 base
  float z[3 * R];
#pragma unroll
  for (int u = 0; u < 6; ++u) {
    f32x4 d = buf[7 * t + u];
    z[4 * u] = d.x; z[4 * u + 1] = d.y; z[4 * u + 2] = d.z; z[4 * u + 3] = d.w;
  }

  // per-thread aggregates: A = sum z, W = sum (R-1-e)*z
  float tS[3] = {0, 0, 0}, tT[3] = {0, 0, 0};
#pragma unroll
  for (int e = 0; e < R; ++e) {
    const float wt = (float)(R - 1 - e);
#pragma unroll
    for (int q = 0; q < 3; ++q) { float v = z[3 * e + q]; tS[q] += v; tT[q] += wt * v; }
  }
  // wave Kogge-Stone with (A,W) operator
#pragma unroll
  for (int d = 1; d < 64; d <<= 1) {
    float pS[3], pT[3];
#pragma unroll
    for (int q = 0; q < 3; ++q) { pS[q] = __shfl_up(tS[q], d); pT[q] = __shfl_up(tT[q], d); }
    if (lane >= d) {
      const float Ld = (float)(R * d);
#pragma unroll
      for (int q = 0; q < 3; ++q) { tT[q] = pT[q] + Ld * pS[q] + tT[q]; tS[q] += pS[q]; }
    }
  }
  float eS[3], eT[3];
#pragma unroll
  for (int q = 0; q < 3; ++q) { eS[q] = __shfl_up(tS[q], 1); eT[q] = __shfl_up(tT[q], 1); }
  if (lane == 0) {
#pragma unroll
    for (int q = 0; q < 3; ++q) { eS[q] = 0.f; eT[q] = 0.f; }
  }
  if (lane == 63) {
#pragma unroll
    for (int q = 0; q < 3; ++q) { wag[wid][q] = tS[q]; wag[wid][3 + q] = tT[q]; }
  }
  __syncthreads();                               // barrier 2 (last block-wide sync)
  float oS[3] = {0, 0, 0}, oT[3] = {0, 0, 0};
  for (int w = 0; w < wid; ++w) {        // wave segment = 64*R = 512
#pragma unroll
    for (int q = 0; q < 3; ++q) oT[q] = oT[q] + 512.0f * oS[q] + wag[w][3 + q];
#pragma unroll
    for (int q = 0; q < 3; ++q) oS[q] += wag[w][q];
  }
  // absolute thread-entry (E0, H0)
  float E0[3], H0[3];
#pragma unroll
  for (int q = 0; q < 3; ++q) {
    E0[q] = Wg[q] + oS[q] + eS[q];
    H0[q] = Wg[3 + q] + (float)(R * t) * Wg[q] + (oT[q] + (float)(R * lane) * oS[q] + eT[q]);
  }

  // ---- 3. fused epilogue: p -> own LDS slots (thread-local WAR), v -> registers
  const float a1 = DTc * Cc, a2 = 0.5f * DTc * Cc, c3 = 0.5f * DTc * GZ;
  float lsum[3] = {0, 0, 0};
  float runH[3] = {H0[0], H0[1], H0[2]};
  float ve[3 * R];
#pragma unroll
  for (int g = 0; g < 2; ++g) {
    float pe[12];
#pragma unroll
    for (int e4 = 0; e4 < 4; ++e4) {
      const int e = 4 * g + e4;
      const float n1 = (float)(int)(start + t * R + e + 1);   // <= 2^23, exact
      float S_[3], T_[3];
#pragma unroll
      for (int q = 0; q < 3; ++q) {
        const float curE = E0[q] + lsum[q];    // E_i
        runH[q] += curE;                       // H_i
        S_[q] = f0[q] + curE;
        T_[q] = n1 * f0[q] + runH[q];
        lsum[q] += z[3 * e + q];
      }
      ve[3 * e + 0] = v0x + Cc * S_[0];
      ve[3 * e + 1] = v0y + Cc * S_[1];
      ve[3 * e + 2] = v0z + Cc * S_[2] + GZ * n1;
      pe[3 * e4 + 0] = p0x + DTc * n1 * v0x + a1 * T_[0] - a2 * S_[0];
      pe[3 * e4 + 1] = p0y + DTc * n1 * v0y + a1 * T_[1] - a2 * S_[1];
      pe[3 * e4 + 2] = p0z + DTc * n1 * v0z + a1 * T_[2] - a2 * S_[2] + c3 * n1 * n1;
    }
#pragma unroll
    for (int u = 0; u < 3; ++u) {
      f32x4 pv = {pe[4 * u], pe[4 * u + 1], pe[4 * u + 2], pe[4 * u + 3]};
      buf[7 * t + 3 * g + u] = pv;
    }
  }

  // ---- 4. wave-local p store: drain this wave's DS writes, read own region, nt store
  asm volatile("s_waitcnt lgkmcnt(0)" ::: "memory");
  {
    f32x4* dst = (f32x4*)out + (size_t)NF4 * b + 384 * wid;
#pragma unroll
    for (int it = 0; it < 6; ++it) {
      const int j = it * 64 + lane;              // 0..383 within wave's p range
      f32x4 d = buf[448 * wid + physf4(j)];
      __builtin_nontemporal_store(d, dst + j);
    }
  }

  // ---- 5. v through the same wave region (thread-local WAR after reads drained)
  asm volatile("s_waitcnt lgkmcnt(0)" ::: "memory");
#pragma unroll
  for (int u = 0; u < 6; ++u) {
    f32x4 vv = {ve[4 * u], ve[4 * u + 1], ve[4 * u + 2], ve[4 * u + 3]};
    buf[7 * t + u] = vv;
  }
  asm volatile("s_waitcnt lgkmcnt(0)" ::: "memory");
  {
    f32x4* dst = (f32x4*)(out + (size_t)3 * KE) + (size_t)NF4 * b + 384 * wid;
#pragma unroll
    for (int it = 0; it < 6; ++it) {
      const int j = it * 64 + lane;
      f32x4 d = buf[448 * wid + physf4(j)];
      __builtin_nontemporal_store(d, dst + j);
    }
  }
}

extern "C" void kernel_launch(void* const* d_in, const int* in_sizes, int n_in,
                              void* d_out, int out_size, void* d_ws, size_t ws_size,
                              hipStream_t stream) {
  const float* f  = (const float*)d_in[0];
  const float* p0 = (const float*)d_in[1];
  const float* v0 = (const float*)d_in[2];
  float* out = (float*)d_out;
  float* W   = (float*)d_ws;            // 6*NB floats: A[3][NB], Bw[3][NB]
  float* W2  = W + 6 * NB;              // 6*NB floats: per-chunk (Eg[3], Hg[3])
  k_agg <<<NB, BLOCK, 0, stream>>>(f, W);
  k_pre <<<1, PRET, 0, stream>>>(W, W2);
  k_scan<<<NB, BLOCK, 0, stream>>>(f, W2, p0, v0, out);
}

// Round 11
// 69.180 us; speedup vs baseline: 3.2350x; 1.0895x over previous
//
#include <hip/hip_runtime.h>

// p/v trajectory double-scan, K = 2^23 fp32 3-vectors. TWO kernels: reduce, then scan
// (scan recomputes its cross-chunk prefix redundantly from the 96 KB L2-resident W).
// Aligned-stream formulation: z_m = f[m]; E_i = excl prefix(z); H_i = sum_{m<=i} E_m.
// S_i = f0 + E_i, T_i = (i+1) f0 + H_i;
//   v_i = v0 + Cc*S_i + GZ*(i+1) e3
//   p_i = p0 + DT*(i+1)*v0 + DT*Cc*T_i - DT/2*Cc*S_i + DT/2*GZ*(i+1)^2 e3
// Cross-chunk prefix (order-independent, per block b):
//   Eg(b) = sum_{c<b} A_c
//   Hg(b) = sum_{c<b} [ ((b-1-c)*2048 + 2047)*A_c - Bw_c ]     (weights < 2^24, exact f32)
// Lessons: r3 — nt strided stores amplify HBM writes 2.6x; r8 — cached strided stores
//   cost +14us (L2 request fan-out): outputs leave lane-consecutive via LDS+nt.
//   r5/r9 — agent-scope handshakes serialize ~60ns/block across 8 XCDs: NO cross-block
//   sync; redundant recompute from L2-hot data instead. r6 — strided input loads and
//   tiny k_agg blocks regress. r10 — k_scan is BW-bound (302MB ~= 45-48us floor).

namespace {
constexpr int  KE    = 8388608;               // 2^23
constexpr int  CHUNK = 2048;                  // elements per scan block
constexpr int  NB    = KE / CHUNK;            // 4096
constexpr int  BLOCK = 256;
constexpr int  R     = CHUNK / BLOCK;         // 8 elements/thread
constexpr int  NF4   = 3 * CHUNK / 4;         // 1536 f4 per chunk per output
constexpr int  CPT   = NB / BLOCK;            // 16 chunk-entries per thread in phase A
constexpr float DTc = 0.01f;
constexpr float Cc  = 0.01f / 1.5f;           // DT/M
constexpr float GZ  = -0.01f * 9.81f;         // DT * (-G)
typedef float f32x4 __attribute__((ext_vector_type(4)));
__device__ __forceinline__ int physf4(int q) { return 7 * (q / 6) + q % 6; }
}

// ---------- k_agg: per-chunk A = sum z, Bw = sum j*z  (r4-proven geometry) ----------
__global__ __launch_bounds__(BLOCK) void k_agg(const float* __restrict__ f,
                                               float* __restrict__ W) {
  const int b = blockIdx.x, t = threadIdx.x;
  const int lane = t & 63, wid = t >> 6;
  const f32x4* src = (const f32x4*)(f + (size_t)3 * CHUNK * b);
  float A[3] = {0.f, 0.f, 0.f}, Bw[3] = {0.f, 0.f, 0.f};
#pragma unroll
  for (int it = 0; it < 2; ++it) {
    int q3 = it * BLOCK + t;                  // triple index, elems 4q3..4q3+3
    f32x4 d0 = src[3 * q3], d1 = src[3 * q3 + 1], d2 = src[3 * q3 + 2];
    float j0 = (float)(4 * q3), j1 = j0 + 1.f, j2 = j0 + 2.f, j3 = j0 + 3.f;
    A[0] += d0.x; Bw[0] += j0 * d0.x;  A[1] += d0.y; Bw[1] += j0 * d0.y;  A[2] += d0.z; Bw[2] += j0 * d0.z;
    A[0] += d0.w; Bw[0] += j1 * d0.w;  A[1] += d1.x; Bw[1] += j1 * d1.x;  A[2] += d1.y; Bw[2] += j1 * d1.y;
    A[0] += d1.z; Bw[0] += j2 * d1.z;  A[1] += d1.w; Bw[1] += j2 * d1.w;  A[2] += d2.x; Bw[2] += j2 * d2.x;
    A[0] += d2.y; Bw[0] += j3 * d2.y;  A[1] += d2.z; Bw[1] += j3 * d2.z;  A[2] += d2.w; Bw[2] += j3 * d2.w;
  }
#pragma unroll
  for (int d = 32; d >= 1; d >>= 1) {
#pragma unroll
    for (int q = 0; q < 3; ++q) {
      A[q]  += __shfl_down(A[q], d);
      Bw[q] += __shfl_down(Bw[q], d);
    }
  }
  __shared__ float wag[4][6];
  if (lane == 0) {
#pragma unroll
    for (int q = 0; q < 3; ++q) { wag[wid][q] = A[q]; wag[wid][3 + q] = Bw[q]; }
  }
  __syncthreads();
  if (t == 0) {
#pragma unroll
    for (int q = 0; q < 3; ++q) {
      W[q * NB + b]       = wag[0][q] + wag[1][q] + wag[2][q] + wag[3][q];
      W[(3 + q) * NB + b] = wag[0][3 + q] + wag[1][3 + q] + wag[2][3 + q] + wag[3][3 + q];
    }
  }
}

// ---------- k_scan: staged input + in-block phase-A prefix + scan + wave-local output ----------
__global__ __launch_bounds__(BLOCK, 5) void k_scan(const float* __restrict__ f,
                                                   const float* __restrict__ W,
                                                   const float* __restrict__ p0v,
                                                   const float* __restrict__ v0v,
                                                   float* __restrict__ out) {
  const int b = blockIdx.x, t = threadIdx.x;
  const int lane = t & 63, wid = t >> 6;
  const long start = (long)b * CHUNK;

  const float f0[3] = {f[0], f[1], f[2]};
  const float p0x = p0v[0], p0y = p0v[1], p0z = p0v[2];
  const float v0x = v0v[0], v0y = v0v[1], v0z = v0v[2];

  __shared__ f32x4 buf[7 * BLOCK];    // 28672 B padded transpose buffer
  __shared__ float wag[4][6];
  __shared__ float pag[4][6];

  // ---- 1. coalesced global load -> LDS (blocked-padded layout); issues first
  {
    const f32x4* src = (const f32x4*)(f + 3 * start);
#pragma unroll
    for (int it = 0; it < 6; ++it) {
      const int q = t + BLOCK * it;
      buf[physf4(q)] = src[q];
    }
  }

  // ---- 1b. phase A: redundant cross-chunk prefix from L2-resident W (96 KB)
  //      Eg = sum_{c<b} A_c ; Hg = sum_{c<b} [((b-1-c)*2048+2047)*A_c - Bw_c]
  float Ea[3] = {0.f, 0.f, 0.f}, Ha[3] = {0.f, 0.f, 0.f};
#pragma unroll
  for (int k = 0; k < CPT; ++k) {
    const int c = t + BLOCK * k;               // coalesced across threads
    const bool sel = (c < b);
    const float ws = sel ? ((float)(b - 1 - c) * 2048.f + 2047.f) : 0.f;
#pragma unroll
    for (int q = 0; q < 3; ++q) {
      const float a  = W[q * NB + c];
      const float bw = W[(3 + q) * NB + c];
      Ea[q] += sel ? a : 0.f;
      Ha[q] += ws * a - (sel ? bw : 0.f);
    }
  }
#pragma unroll
  for (int d = 32; d >= 1; d >>= 1) {
#pragma unroll
    for (int q = 0; q < 3; ++q) {
      Ea[q] += __shfl_down(Ea[q], d);
      Ha[q] += __shfl_down(Ha[q], d);
    }
  }
  if (lane == 0) {
#pragma unroll
    for (int q = 0; q < 3; ++q) { pag[wid][q] = Ea[q]; pag[wid][3 + q] = Ha[q]; }
  }
  __syncthreads();                             // barrier 1: staging + pag complete
  float Eg[3], Hg[3];
#pragma unroll
  for (int q = 0; q < 3; ++q) {
    Eg[q] = pag[0][q] + pag[1][q] + pag[2][q] + pag[3][q];
    Hg[q] = pag[0][3 + q] + pag[1][3 + q] + pag[2][3 + q] + pag[3][3 + q];
  }

  // ---- 2. thread's 8 elements = 6 float4 LDS reads at stride-7 base
  float z[3 * R];
#pragma unroll
  for (int u = 0; u < 6; ++u) {
    f32x4 d = buf[7 * t + u];
    z[4 * u] = d.x; z[4 * u + 1] = d.y; z[4 * u + 2] = d.z; z[4 * u + 3] = d.w;
  }

  // per-thread aggregates: A = sum z, W = sum (R-1-e)*z
  float tS[3] = {0, 0, 0}, tT[3] = {0, 0, 0};
#pragma unroll
  for (int e = 0; e < R; ++e) {
    const float wt = (float)(R - 1 - e);
#pragma unroll
    for (int q = 0; q < 3; ++q) { float v = z[3 * e + q]; tS[q] += v; tT[q] += wt * v; }
  }
  // wave Kogge-Stone with (A,W) operator
#pragma unroll
  for (int d = 1; d < 64; d <<= 1) {
    float pS[3], pT[3];
#pragma unroll
    for (int q = 0; q < 3; ++q) { pS[q] = __shfl_up(tS[q], d); pT[q] = __shfl_up(tT[q], d); }
    if (lane >= d) {
      const float Ld = (float)(R * d);
#pragma unroll
      for (int q = 0; q < 3; ++q) { tT[q] = pT[q] + Ld * pS[q] + tT[q]; tS[q] += pS[q]; }
    }
  }
  float eS[3], eT[3];
#pragma unroll
  for (int q = 0; q < 3; ++q) { eS[q] = __shfl_up(tS[q], 1); eT[q] = __shfl_up(tT[q], 1); }
  if (lane == 0) {
#pragma unroll
    for (int q = 0; q < 3; ++q) { eS[q] = 0.f; eT[q] = 0.f; }
  }
  if (lane == 63) {
#pragma unroll
    for (int q = 0; q < 3; ++q) { wag[wid][q] = tS[q]; wag[wid][3 + q] = tT[q]; }
  }
  __syncthreads();                             // barrier 2 (last block-wide sync)
  float oS[3] = {0, 0, 0}, oT[3] = {0, 0, 0};
  for (int w = 0; w < wid; ++w) {              // wave segment = 64*R = 512
#pragma unroll
    for (int q = 0; q < 3; ++q) oT[q] = oT[q] + 512.0f * oS[q] + wag[w][3 + q];
#pragma unroll
    for (int q = 0; q < 3; ++q) oS[q] += wag[w][q];
  }
  // absolute thread-entry (E0, H0)
  float E0[3], H0[3];
#pragma unroll
  for (int q = 0; q < 3; ++q) {
    E0[q] = Eg[q] + oS[q] + eS[q];
    H0[q] = Hg[q] + (float)(R * t) * Eg[q] + (oT[q] + (float)(R * lane) * oS[q] + eT[q]);
  }

  // ---- 3. fused epilogue: p -> own LDS slots (thread-local WAR), v -> registers
  const float a1 = DTc * Cc, a2 = 0.5f * DTc * Cc, c3 = 0.5f * DTc * GZ;
  float lsum[3] = {0, 0, 0};
  float runH[3] = {H0[0], H0[1], H0[2]};
  float ve[3 * R];
#pragma unroll
  for (int g = 0; g < 2; ++g) {
    float pe[12];
#pragma unroll
    for (int e4 = 0; e4 < 4; ++e4) {
      const int e = 4 * g + e4;
      const float n1 = (float)(int)(start + t * R + e + 1);   // <= 2^23, exact
      float S_[3], T_[3];
#pragma unroll
      for (int q = 0; q < 3; ++q) {
        const float curE = E0[q] + lsum[q];    // E_i
        runH[q] += curE;                       // H_i
        S_[q] = f0[q] + curE;
        T_[q] = n1 * f0[q] + runH[q];
        lsum[q] += z[3 * e + q];
      }
      ve[3 * e + 0] = v0x + Cc * S_[0];
      ve[3 * e + 1] = v0y + Cc * S_[1];
      ve[3 * e + 2] = v0z + Cc * S_[2] + GZ * n1;
      pe[3 * e4 + 0] = p0x + DTc * n1 * v0x + a1 * T_[0] - a2 * S_[0];
      pe[3 * e4 + 1] = p0y + DTc * n1 * v0y + a1 * T_[1] - a2 * S_[1];
      pe[3 * e4 + 2] = p0z + DTc * n1 * v0z + a1 * T_[2] - a2 * S_[2] + c3 * n1 * n1;
    }
#pragma unroll
    for (int u = 0; u < 3; ++u) {
      f32x4 pv = {pe[4 * u], pe[4 * u + 1], pe[4 * u + 2], pe[4 * u + 3]};
      buf[7 * t + 3 * g + u] = pv;
    }
  }

  // ---- 4. wave-local p store: drain this wave's DS writes, read own region, nt store
  asm volatile("s_waitcnt lgkmcnt(0)" ::: "memory");
  {
    f32x4* dst = (f32x4*)out + (size_t)NF4 * b + 384 * wid;
#pragma unroll
    for (int it = 0; it < 6; ++it) {
      const int j = it * 64 + lane;              // 0..383 within wave's p range
      f32x4 d = buf[448 * wid + physf4(j)];
      __builtin_nontemporal_store(d, dst + j);
    }
  }

  // ---- 5. v through the same wave region (thread-local WAR after reads drained)
  asm volatile("s_waitcnt lgkmcnt(0)" ::: "memory");
#pragma unroll
  for (int u = 0; u < 6; ++u) {
    f32x4 vv = {ve[4 * u], ve[4 * u + 1], ve[4 * u + 2], ve[4 * u + 3]};
    buf[7 * t + u] = vv;
  }
  asm volatile("s_waitcnt lgkmcnt(0)" ::: "memory");
  {
    f32x4* dst = (f32x4*)(out + (size_t)3 * KE) + (size_t)NF4 * b + 384 * wid;
#pragma unroll
    for (int it = 0; it < 6; ++it) {
      const int j = it * 64 + lane;
      f32x4 d = buf[448 * wid + physf4(j)];
      __builtin_nontemporal_store(d, dst + j);
    }
  }
}

extern "C" void kernel_launch(void* const* d_in, const int* in_sizes, int n_in,
                              void* d_out, int out_size, void* d_ws, size_t ws_size,
                              hipStream_t stream) {
  const float* f  = (const float*)d_in[0];
  const float* p0 = (const float*)d_in[1];
  const float* v0 = (const float*)d_in[2];
  float* out = (float*)d_out;
  float* W   = (float*)d_ws;            // 6*NB floats: A[3][NB], Bw[3][NB] (96 KB)
  k_agg <<<NB, BLOCK, 0, stream>>>(f, W);
  k_scan<<<NB, BLOCK, 0, stream>>>(f, W, p0, v0, out);
}

// Round 12
// 67.963 us; speedup vs baseline: 3.2929x; 1.0179x over previous
//
#include <hip/hip_runtime.h>

// p/v trajectory double-scan, K = 2^23 fp32 3-vectors. TWO kernels: reduce, then scan
// (scan recomputes its cross-chunk prefix redundantly from the 96 KB L2-resident W).
// Aligned-stream formulation: z_m = f[m]; E_i = excl prefix(z); H_i = sum_{m<=i} E_m.
// S_i = f0 + E_i, T_i = (i+1) f0 + H_i;
//   v_i = v0 + Cc*S_i + GZ*(i+1) e3
//   p_i = p0 + DT*(i+1)*v0 + DT*Cc*T_i - DT/2*Cc*S_i + DT/2*GZ*(i+1)^2 e3
// Cross-chunk prefix (order-independent, per block b):
//   Eg(b) = sum_{c<b} A_c
//   Hg(b) = sum_{c<b} [ ((b-1-c)*2048 + 2047)*A_c - Bw_c ]     (weights < 2^24, exact f32)
// Lessons: r3 — nt strided stores amplify HBM writes 2.6x; r8 — cached strided stores
//   cost +14us (L2 request fan-out): outputs leave lane-consecutive via LDS+nt.
//   r5/r9 — agent-scope handshakes serialize across the 8 XCDs: NO cross-block sync;
//   redundant recompute from L2-hot data instead. r6 — strided input loads in k_scan and
//   tiny k_agg blocks regress. r10 — k_scan is BW-bound (302MB ~= 45-48us floor).
// r12: k_agg wave-per-chunk (no LDS/barrier, 4 chunks/block) to shave fixed overhead.

namespace {
constexpr int  KE    = 8388608;               // 2^23
constexpr int  CHUNK = 2048;                  // elements per scan block
constexpr int  NB    = KE / CHUNK;            // 4096
constexpr int  BLOCK = 256;
constexpr int  R     = CHUNK / BLOCK;         // 8 elements/thread
constexpr int  NF4   = 3 * CHUNK / 4;         // 1536 f4 per chunk per output
constexpr int  CPT   = NB / BLOCK;            // 16 chunk-entries per thread in phase A
constexpr float DTc = 0.01f;
constexpr float Cc  = 0.01f / 1.5f;           // DT/M
constexpr float GZ  = -0.01f * 9.81f;         // DT * (-G)
typedef float f32x4 __attribute__((ext_vector_type(4)));
__device__ __forceinline__ int physf4(int q) { return 7 * (q / 6) + q % 6; }
}

// ---------- k_agg: wave-per-chunk A = sum z, Bw = sum j*z (no LDS, no barrier) ----------
__global__ __launch_bounds__(BLOCK) void k_agg(const float* __restrict__ f,
                                               float* __restrict__ W) {
  const int t = threadIdx.x, lane = t & 63, wid = t >> 6;
  const int c = 4 * blockIdx.x + wid;           // this wave's chunk
  const f32x4* src = (const f32x4*)f + (size_t)NF4 * c;
  float A[3] = {0.f, 0.f, 0.f}, Bw[3] = {0.f, 0.f, 0.f};
#pragma unroll
  for (int it = 0; it < 8; ++it) {
    const int q3 = it * 64 + lane;              // triple index 0..511, elems 4q3..4q3+3
    f32x4 d0 = src[3 * q3], d1 = src[3 * q3 + 1], d2 = src[3 * q3 + 2];
    const float j0 = (float)(4 * q3), j1 = j0 + 1.f, j2 = j0 + 2.f, j3 = j0 + 3.f;
    A[0] += d0.x; Bw[0] += j0 * d0.x;  A[1] += d0.y; Bw[1] += j0 * d0.y;  A[2] += d0.z; Bw[2] += j0 * d0.z;
    A[0] += d0.w; Bw[0] += j1 * d0.w;  A[1] += d1.x; Bw[1] += j1 * d1.x;  A[2] += d1.y; Bw[2] += j1 * d1.y;
    A[0] += d1.z; Bw[0] += j2 * d1.z;  A[1] += d1.w; Bw[1] += j2 * d1.w;  A[2] += d2.x; Bw[2] += j2 * d2.x;
    A[0] += d2.y; Bw[0] += j3 * d2.y;  A[1] += d2.z; Bw[1] += j3 * d2.z;  A[2] += d2.w; Bw[2] += j3 * d2.w;
  }
#pragma unroll
  for (int d = 32; d >= 1; d >>= 1) {
#pragma unroll
    for (int q = 0; q < 3; ++q) {
      A[q]  += __shfl_down(A[q], d);
      Bw[q] += __shfl_down(Bw[q], d);
    }
  }
  if (lane == 0) {
#pragma unroll
    for (int q = 0; q < 3; ++q) {
      W[q * NB + c]       = A[q];
      W[(3 + q) * NB + c] = Bw[q];
    }
  }
}

// ---------- k_scan: staged input + in-block phase-A prefix + scan + wave-local output ----------
__global__ __launch_bounds__(BLOCK, 5) void k_scan(const float* __restrict__ f,
                                                   const float* __restrict__ W,
                                                   const float* __restrict__ p0v,
                                                   const float* __restrict__ v0v,
                                                   float* __restrict__ out) {
  const int b = blockIdx.x, t = threadIdx.x;
  const int lane = t & 63, wid = t >> 6;
  const long start = (long)b * CHUNK;

  const float f0[3] = {f[0], f[1], f[2]};
  const float p0x = p0v[0], p0y = p0v[1], p0z = p0v[2];
  const float v0x = v0v[0], v0y = v0v[1], v0z = v0v[2];

  __shared__ f32x4 buf[7 * BLOCK];    // 28672 B padded transpose buffer
  __shared__ float wag[4][6];
  __shared__ float pag[4][6];

  // ---- 1. coalesced global load -> LDS (blocked-padded layout); issues first
  {
    const f32x4* src = (const f32x4*)(f + 3 * start);
#pragma unroll
    for (int it = 0; it < 6; ++it) {
      const int q = t + BLOCK * it;
      buf[physf4(q)] = src[q];
    }
  }

  // ---- 1b. phase A: redundant cross-chunk prefix from L2-resident W (96 KB)
  //      Eg = sum_{c<b} A_c ; Hg = sum_{c<b} [((b-1-c)*2048+2047)*A_c - Bw_c]
  float Ea[3] = {0.f, 0.f, 0.f}, Ha[3] = {0.f, 0.f, 0.f};
#pragma unroll
  for (int k = 0; k < CPT; ++k) {
    const int c = t + BLOCK * k;               // coalesced across threads
    const bool sel = (c < b);
    const float ws = sel ? ((float)(b - 1 - c) * 2048.f + 2047.f) : 0.f;
#pragma unroll
    for (int q = 0; q < 3; ++q) {
      const float a  = W[q * NB + c];
      const float bw = W[(3 + q) * NB + c];
      Ea[q] += sel ? a : 0.f;
      Ha[q] += ws * a - (sel ? bw : 0.f);
    }
  }
#pragma unroll
  for (int d = 32; d >= 1; d >>= 1) {
#pragma unroll
    for (int q = 0; q < 3; ++q) {
      Ea[q] += __shfl_down(Ea[q], d);
      Ha[q] += __shfl_down(Ha[q], d);
    }
  }
  if (lane == 0) {
#pragma unroll
    for (int q = 0; q < 3; ++q) { pag[wid][q] = Ea[q]; pag[wid][3 + q] = Ha[q]; }
  }
  __syncthreads();                             // barrier 1: staging + pag complete
  float Eg[3], Hg[3];
#pragma unroll
  for (int q = 0; q < 3; ++q) {
    Eg[q] = pag[0][q] + pag[1][q] + pag[2][q] + pag[3][q];
    Hg[q] = pag[0][3 + q] + pag[1][3 + q] + pag[2][3 + q] + pag[3][3 + q];
  }

  // ---- 2. thread's 8 elements = 6 float4 LDS reads at stride-7 base
  float z[3 * R];
#pragma unroll
  for (int u = 0; u < 6; ++u) {
    f32x4 d = buf[7 * t + u];
    z[4 * u] = d.x; z[4 * u + 1] = d.y; z[4 * u + 2] = d.z; z[4 * u + 3] = d.w;
  }

  // per-thread aggregates: A = sum z, W = sum (R-1-e)*z
  float tS[3] = {0, 0, 0}, tT[3] = {0, 0, 0};
#pragma unroll
  for (int e = 0; e < R; ++e) {
    const float wt = (float)(R - 1 - e);
#pragma unroll
    for (int q = 0; q < 3; ++q) { float v = z[3 * e + q]; tS[q] += v; tT[q] += wt * v; }
  }
  // wave Kogge-Stone with (A,W) operator
#pragma unroll
  for (int d = 1; d < 64; d <<= 1) {
    float pS[3], pT[3];
#pragma unroll
    for (int q = 0; q < 3; ++q) { pS[q] = __shfl_up(tS[q], d); pT[q] = __shfl_up(tT[q], d); }
    if (lane >= d) {
      const float Ld = (float)(R * d);
#pragma unroll
      for (int q = 0; q < 3; ++q) { tT[q] = pT[q] + Ld * pS[q] + tT[q]; tS[q] += pS[q]; }
    }
  }
  float eS[3], eT[3];
#pragma unroll
  for (int q = 0; q < 3; ++q) { eS[q] = __shfl_up(tS[q], 1); eT[q] = __shfl_up(tT[q], 1); }
  if (lane == 0) {
#pragma unroll
    for (int q = 0; q < 3; ++q) { eS[q] = 0.f; eT[q] = 0.f; }
  }
  if (lane == 63) {
#pragma unroll
    for (int q = 0; q < 3; ++q) { wag[wid][q] = tS[q]; wag[wid][3 + q] = tT[q]; }
  }
  __syncthreads();                             // barrier 2 (last block-wide sync)
  float oS[3] = {0, 0, 0}, oT[3] = {0, 0, 0};
  for (int w = 0; w < wid; ++w) {              // wave segment = 64*R = 512
#pragma unroll
    for (int q = 0; q < 3; ++q) oT[q] = oT[q] + 512.0f * oS[q] + wag[w][3 + q];
#pragma unroll
    for (int q = 0; q < 3; ++q) oS[q] += wag[w][q];
  }
  // absolute thread-entry (E0, H0)
  float E0[3], H0[3];
#pragma unroll
  for (int q = 0; q < 3; ++q) {
    E0[q] = Eg[q] + oS[q] + eS[q];
    H0[q] = Hg[q] + (float)(R * t) * Eg[q] + (oT[q] + (float)(R * lane) * oS[q] + eT[q]);
  }

  // ---- 3. fused epilogue: p -> own LDS slots (thread-local WAR), v -> registers
  const float a1 = DTc * Cc, a2 = 0.5f * DTc * Cc, c3 = 0.5f * DTc * GZ;
  float lsum[3] = {0, 0, 0};
  float runH[3] = {H0[0], H0[1], H0[2]};
  float ve[3 * R];
#pragma unroll
  for (int g = 0; g < 2; ++g) {
    float pe[12];
#pragma unroll
    for (int e4 = 0; e4 < 4; ++e4) {
      const int e = 4 * g + e4;
      const float n1 = (float)(int)(start + t * R + e + 1);   // <= 2^23, exact
      float S_[3], T_[3];
#pragma unroll
      for (int q = 0; q < 3; ++q) {
        const float curE = E0[q] + lsum[q];    // E_i
        runH[q] += curE;                       // H_i
        S_[q] = f0[q] + curE;
        T_[q] = n1 * f0[q] + runH[q];
        lsum[q] += z[3 * e + q];
      }
      ve[3 * e + 0] = v0x + Cc * S_[0];
      ve[3 * e + 1] = v0y + Cc * S_[1];
      ve[3 * e + 2] = v0z + Cc * S_[2] + GZ * n1;
      pe[3 * e4 + 0] = p0x + DTc * n1 * v0x + a1 * T_[0] - a2 * S_[0];
      pe[3 * e4 + 1] = p0y + DTc * n1 * v0y + a1 * T_[1] - a2 * S_[1];
      pe[3 * e4 + 2] = p0z + DTc * n1 * v0z + a1 * T_[2] - a2 * S_[2] + c3 * n1 * n1;
    }
#pragma unroll
    for (int u = 0; u < 3; ++u) {
      f32x4 pv = {pe[4 * u], pe[4 * u + 1], pe[4 * u + 2], pe[4 * u + 3]};
      buf[7 * t + 3 * g + u] = pv;
    }
  }

  // ---- 4. wave-local p store: drain this wave's DS writes, read own region, nt store
  asm volatile("s_waitcnt lgkmcnt(0)" ::: "memory");
  {
    f32x4* dst = (f32x4*)out + (size_t)NF4 * b + 384 * wid;
#pragma unroll
    for (int it = 0; it < 6; ++it) {
      const int j = it * 64 + lane;              // 0..383 within wave's p range
      f32x4 d = buf[448 * wid + physf4(j)];
      __builtin_nontemporal_store(d, dst + j);
    }
  }

  // ---- 5. v through the same wave region (thread-local WAR after reads drained)
  asm volatile("s_waitcnt lgkmcnt(0)" ::: "memory");
#pragma unroll
  for (int u = 0; u < 6; ++u) {
    f32x4 vv = {ve[4 * u], ve[4 * u + 1], ve[4 * u + 2], ve[4 * u + 3]};
    buf[7 * t + u] = vv;
  }
  asm volatile("s_waitcnt lgkmcnt(0)" ::: "memory");
  {
    f32x4* dst = (f32x4*)(out + (size_t)3 * KE) + (size_t)NF4 * b + 384 * wid;
#pragma unroll
    for (int it = 0; it < 6; ++it) {
      const int j = it * 64 + lane;
      f32x4 d = buf[448 * wid + physf4(j)];
      __builtin_nontemporal_store(d, dst + j);
    }
  }
}

extern "C" void kernel_launch(void* const* d_in, const int* in_sizes, int n_in,
                              void* d_out, int out_size, void* d_ws, size_t ws_size,
                              hipStream_t stream) {
  const float* f  = (const float*)d_in[0];
  const float* p0 = (const float*)d_in[1];
  const float* v0 = (const float*)d_in[2];
  float* out = (float*)d_out;
  float* W   = (float*)d_ws;            // 6*NB floats: A[3][NB], Bw[3][NB] (96 KB)
  k_agg <<<NB / 4, BLOCK, 0, stream>>>(f, W);
  k_scan<<<NB, BLOCK, 0, stream>>>(f, W, p0, v0, out);
}